// Round 14
// baseline (10852.400 us; speedup 1.0000x reference)
//
#include <hip/hip_runtime.h>
#include <hip/hip_cooperative_groups.h>

namespace cg = cooperative_groups;

typedef _Float16 f16;
typedef _Float16 half8 __attribute__((ext_vector_type(8)));
typedef float float4v __attribute__((ext_vector_type(4)));
typedef int int4v __attribute__((ext_vector_type(4)));

constexpr int kB  = 512;   // batch
constexpr int kT  = 512;   // seq len
constexpr int kI  = 128;   // input dim
constexpr int kH  = 512;   // hidden
constexpr int kNG = 2048;  // 4*H
constexpr int kO  = 128;   // output dim

// Padded K-stride (f16) for resident W in LDS; conflict-free b128 (verified R5).
constexpr int LDK = 650;

__device__ __forceinline__ float fsig(float v)  { return 1.0f / (1.0f + __expf(-v)); }
__device__ __forceinline__ float ftanh(float v) { return 1.0f - 2.0f / (1.0f + __expf(2.0f * v)); }

union h8u { half8 h; int4v i; };
union f16u { f16 f; unsigned short s; };

// R14: DUAL-CHAIN latency hiding. 128 WGs x 256 threads, cooperative.
// WG (p = wg>>5 in 0..3, ng = wg&31) serves TWO independent recurrence chains:
// bg = p and bg = p+4 (batch rows bg*64..+63, h-cols ng*16..+15). Both chains
// share the SAME w_lds slice (weights depend only on ng). Per iteration:
// [poll_p, compute p, publish p, xacc_p shadow] [poll_q, compute q, publish q,
// xacc_q shadow] -- each chain's publish->re-poll gap is filled by the other
// chain's full compute segment, hiding the IF$ rendezvous latency that R6-R13
// paid exposed (5 barrier variants all ~11us/step => latency, not mechanics).
// Barrier mechanics = R7 exactly (best measured): sc1 h-stores, syncthreads
// drain, tid0 publish, 32-slot wave-parallel poll, all relaxed-agent (sc1 =
// IF$ coherence point, the only proven-live path; R11 killed sc0-only).
__global__ __launch_bounds__(256, 1) void lstm_fused(
    const float* __restrict__ x,  const float* __restrict__ Wx,
    const float* __restrict__ Wh, const float* __restrict__ bias,
    const float* __restrict__ Wp, const float* __restrict__ bp,
    float* __restrict__ out, float* __restrict__ ws)
{
  cg::grid_group grid = cg::this_grid();

  __shared__ __align__(16) f16 w_lds[64 * LDK];

  const int tid = threadIdx.x;
  const int wg  = blockIdx.x;
  const int p   = wg >> 5;      // chain pair 0..3
  const int ng  = wg & 31;
  const int wv  = tid >> 6;     // wave 0..3
  const int l   = tid & 63;
  const int lc  = l & 15;       // fragment row/col
  const int lj  = l >> 4;       // k-group 0..3

  const int bgp = p;            // chain 1
  const int bgq = p + 4;        // chain 2

  f16* h16a = (f16*)ws;                          // [512][512] fp16
  f16* h16b = h16a + kB * kH;
  unsigned* flags = (unsigned*)(h16b + kB * kH); // 8 chains x 32 slots x 128B = 32 KB

  // ---- init: zero h0 + flags (ws poisoned; re-init every call). 32768 threads. ----
  {
    int gtid = wg * 256 + tid;                 // 0..32767
    unsigned* z = (unsigned*)h16a;             // 131072 u32 = 512 KB -> 4 per thread
    z[gtid * 4 + 0] = 0u; z[gtid * 4 + 1] = 0u;
    z[gtid * 4 + 2] = 0u; z[gtid * 4 + 3] = 0u;
    if (gtid < 8192) flags[gtid] = 0u;
  }

  // ---- one-time: stage W slice -> LDS fp16 (depends only on ng) ----
  for (int idx = tid; idx < 64 * 640; idx += 256) {
    int c = idx & 63;
    int k = idx >> 6;
    int gcol = (c >> 4) * 512 + ng * 16 + (c & 15);
    float v = (k < 512) ? Wh[(long)k * kNG + gcol]
                        : Wx[(long)(k - 512) * kNG + gcol];
    w_lds[c * LDK + k] = (f16)v;
  }
  float bb[4];
  #pragma unroll
  for (int g = 0; g < 4; ++g) bb[g] = bias[g * 512 + ng * 16 + lc];

  const f16* wbase = w_lds + lc * LDK + lj * 8;

  const int arow_p = bgp * 64 + wv * 16 + lc;
  const int arow_q = bgq * 64 + wv * 16 + lc;
  const float* xrow_p = x + (long)arow_p * (kT * kI) + lj * 8;
  const float* xrow_q = x + (long)arow_q * (kT * kI) + lj * 8;
  const unsigned hoff_p = (unsigned)(arow_p * kH * 2 + lj * 16);
  const unsigned hoff_q = (unsigned)(arow_q * kH * 2 + lj * 16);

  unsigned* slot_p = flags + (unsigned)(bgp * 32 + ng) * 32u;
  unsigned* slot_q = flags + (unsigned)(bgq * 32 + ng) * 32u;
  const unsigned* poll_p = flags + (unsigned)(bgp * 32 + (l & 31)) * 32u;
  const unsigned* poll_q = flags + (unsigned)(bgq * 32 + (l & 31)) * 32u;

  float ce_p[4] = {0.f, 0.f, 0.f, 0.f};
  float ce_q[4] = {0.f, 0.f, 0.f, 0.f};

  grid.sync();   // h zeros + flag zeros globally visible; w_lds staged

  // ---- bootstrap: xacc(0) = bias + x(0)@Wx for both chains ----
  float4v xacc_p[4], xacc_q[4];
  {
    float4v xa[4], xb[4];
    #pragma unroll
    for (int q = 0; q < 4; ++q) {
      xa[q] = *(const float4v*)(xrow_p + q * 32);
      xb[q] = *(const float4v*)(xrow_p + q * 32 + 4);
    }
    #pragma unroll
    for (int g = 0; g < 4; ++g) xacc_p[g] = float4v{bb[g], bb[g], bb[g], bb[g]};
    #pragma unroll
    for (int q = 0; q < 4; ++q) {
      half8 a;
      #pragma unroll
      for (int e = 0; e < 4; ++e) { a[e] = (f16)xa[q][e]; a[e + 4] = (f16)xb[q][e]; }
      #pragma unroll
      for (int g = 0; g < 4; ++g) {
        half8 bf = *(const half8*)(wbase + g * 16 * LDK + 512 + q * 32);
        xacc_p[g] = __builtin_amdgcn_mfma_f32_16x16x32_f16(a, bf, xacc_p[g], 0, 0, 0);
      }
    }
    #pragma unroll
    for (int q = 0; q < 4; ++q) {
      xa[q] = *(const float4v*)(xrow_q + q * 32);
      xb[q] = *(const float4v*)(xrow_q + q * 32 + 4);
    }
    #pragma unroll
    for (int g = 0; g < 4; ++g) xacc_q[g] = float4v{bb[g], bb[g], bb[g], bb[g]};
    #pragma unroll
    for (int q = 0; q < 4; ++q) {
      half8 a;
      #pragma unroll
      for (int e = 0; e < 4; ++e) { a[e] = (f16)xa[q][e]; a[e + 4] = (f16)xb[q][e]; }
      #pragma unroll
      for (int g = 0; g < 4; ++g) {
        half8 bf = *(const half8*)(wbase + g * 16 * LDK + 512 + q * 32);
        xacc_q[g] = __builtin_amdgcn_mfma_f32_16x16x32_f16(a, bf, xacc_q[g], 0, 0, 0);
      }
    }
  }

  // ---- main loop: one iteration advances BOTH chains by one step ----
  for (int t = 0; t < kT; ++t) {
    const f16* hc = (t & 1) ? h16b : h16a;
    f16*       hn = (t & 1) ? h16a : h16b;
    const int  tx1 = (t + 1 < kT) ? (t + 1) : t;   // x index for shadow (clamped)
    const unsigned tgt = (unsigned)t;

    // ================== chain p ==================
    {
      // poll: h_p(t) published by all 32 WGs of chain p (lane covers slot l&31)
      unsigned v;
      do {
        v = __hip_atomic_load(poll_p, __ATOMIC_RELAXED, __HIP_MEMORY_SCOPE_AGENT);
      } while (__all((int)(v >= tgt)) == 0);

      // issue x(t+1) loads (plain, L2/L3-cached) then h(t) loads (sc1, IF$)
      float4v xa[4], xb[4];
      const float* xn = xrow_p + (long)tx1 * kI;
      #pragma unroll
      for (int q = 0; q < 4; ++q) {
        xa[q] = *(const float4v*)(xn + q * 32);
        xb[q] = *(const float4v*)(xn + q * 32 + 4);
      }
      h8u ah[16];
      #pragma unroll
      for (int f = 0; f < 16; ++f) {
        asm volatile("global_load_dwordx4 %0, %1, %2 offset:%c3 sc0 sc1"
                     : "=v"(ah[f].i)
                     : "v"(hoff_p), "s"(hc), "i"(f * 64));
      }
      asm volatile("s_waitcnt vmcnt(0)" ::: "memory");
      __builtin_amdgcn_sched_barrier(0);

      // z = xacc_p(t) + h@Wh
      float4v acc[4];
      #pragma unroll
      for (int g = 0; g < 4; ++g) acc[g] = xacc_p[g];
      #pragma unroll
      for (int ks = 0; ks < 16; ++ks) {
        #pragma unroll
        for (int g = 0; g < 4; ++g) {
          half8 bf = *(const half8*)(wbase + g * 16 * LDK + ks * 32);
          acc[g] = __builtin_amdgcn_mfma_f32_16x16x32_f16(ah[ks].h, bf, acc[g], 0, 0, 0);
        }
      }

      // gates; h stores sc1
      #pragma unroll
      for (int e = 0; e < 4; ++e) {
        float gv = ftanh(acc[0][e]);
        float iv = fsig(acc[1][e]);
        float fv = fsig(acc[2][e]);
        float ov = fsig(acc[3][e]);
        float cn = gv * iv + ce_p[e] * fv;
        ce_p[e] = cn;
        f16u u; u.f = (f16)(ftanh(cn) * ov);
        unsigned short* dst = (unsigned short*)hn
            + (long)(bgp * 64 + wv * 16 + lj * 4 + e) * kH + ng * 16 + lc;
        __hip_atomic_store(dst, u.s, __ATOMIC_RELAXED, __HIP_MEMORY_SCOPE_AGENT);
      }

      __syncthreads();   // all 4 waves' sc1 stores drained (vmcnt0 before barrier)
      if (tid == 0)
        __hip_atomic_store(slot_p, (unsigned)(t + 1), __ATOMIC_RELAXED, __HIP_MEMORY_SCOPE_AGENT);

      // shadow: xacc_p(t+1) = bias + x(t+1)@Wx (regs already loaded)
      #pragma unroll
      for (int g = 0; g < 4; ++g) xacc_p[g] = float4v{bb[g], bb[g], bb[g], bb[g]};
      #pragma unroll
      for (int q = 0; q < 4; ++q) {
        half8 a;
        #pragma unroll
        for (int e = 0; e < 4; ++e) { a[e] = (f16)xa[q][e]; a[e + 4] = (f16)xb[q][e]; }
        #pragma unroll
        for (int g = 0; g < 4; ++g) {
          half8 bf = *(const half8*)(wbase + g * 16 * LDK + 512 + q * 32);
          xacc_p[g] = __builtin_amdgcn_mfma_f32_16x16x32_f16(a, bf, xacc_p[g], 0, 0, 0);
        }
      }
    }

    // ================== chain q (publish->re-poll gap of p is covered here) ==================
    {
      unsigned v;
      do {
        v = __hip_atomic_load(poll_q, __ATOMIC_RELAXED, __HIP_MEMORY_SCOPE_AGENT);
      } while (__all((int)(v >= tgt)) == 0);

      float4v xa[4], xb[4];
      const float* xn = xrow_q + (long)tx1 * kI;
      #pragma unroll
      for (int q = 0; q < 4; ++q) {
        xa[q] = *(const float4v*)(xn + q * 32);
        xb[q] = *(const float4v*)(xn + q * 32 + 4);
      }
      h8u ah[16];
      #pragma unroll
      for (int f = 0; f < 16; ++f) {
        asm volatile("global_load_dwordx4 %0, %1, %2 offset:%c3 sc0 sc1"
                     : "=v"(ah[f].i)
                     : "v"(hoff_q), "s"(hc), "i"(f * 64));
      }
      asm volatile("s_waitcnt vmcnt(0)" ::: "memory");
      __builtin_amdgcn_sched_barrier(0);

      float4v acc[4];
      #pragma unroll
      for (int g = 0; g < 4; ++g) acc[g] = xacc_q[g];
      #pragma unroll
      for (int ks = 0; ks < 16; ++ks) {
        #pragma unroll
        for (int g = 0; g < 4; ++g) {
          half8 bf = *(const half8*)(wbase + g * 16 * LDK + ks * 32);
          acc[g] = __builtin_amdgcn_mfma_f32_16x16x32_f16(ah[ks].h, bf, acc[g], 0, 0, 0);
        }
      }

      #pragma unroll
      for (int e = 0; e < 4; ++e) {
        float gv = ftanh(acc[0][e]);
        float iv = fsig(acc[1][e]);
        float fv = fsig(acc[2][e]);
        float ov = fsig(acc[3][e]);
        float cn = gv * iv + ce_q[e] * fv;
        ce_q[e] = cn;
        f16u u; u.f = (f16)(ftanh(cn) * ov);
        unsigned short* dst = (unsigned short*)hn
            + (long)(bgq * 64 + wv * 16 + lj * 4 + e) * kH + ng * 16 + lc;
        __hip_atomic_store(dst, u.s, __ATOMIC_RELAXED, __HIP_MEMORY_SCOPE_AGENT);
      }

      __syncthreads();
      if (tid == 0)
        __hip_atomic_store(slot_q, (unsigned)(t + 1), __ATOMIC_RELAXED, __HIP_MEMORY_SCOPE_AGENT);

      #pragma unroll
      for (int g = 0; g < 4; ++g) xacc_q[g] = float4v{bb[g], bb[g], bb[g], bb[g]};
      #pragma unroll
      for (int q = 0; q < 4; ++q) {
        half8 a;
        #pragma unroll
        for (int e = 0; e < 4; ++e) { a[e] = (f16)xa[q][e]; a[e + 4] = (f16)xb[q][e]; }
        #pragma unroll
        for (int g = 0; g < 4; ++g) {
          half8 bf = *(const half8*)(wbase + g * 16 * LDK + 512 + q * 32);
          xacc_q[g] = __builtin_amdgcn_mfma_f32_16x16x32_f16(a, bf, xacc_q[g], 0, 0, 0);
        }
      }
    }
  }

  grid.sync();   // all chains done before cross-group projection reads

  // ---- projection + softmax: 4 rows per WG (rows wg*4 .. wg*4+3) ----
  const f16* hf = h16a;   // t=511 (odd) wrote h16a
  float* hrow = (float*)w_lds;             // [2][512] per pass
  float* red  = (float*)w_lds + 2 * kH;
  const int orow = tid >> 7;   // 0..1
  const int oc   = tid & 127;  // 0..127

  for (int pass = 0; pass < 2; ++pass) {
    const int rbase = wg * 4 + pass * 2;
    __syncthreads();
    for (int i = tid; i < 2 * kH; i += 256) {
      int r = i >> 9, k = i & 511;
      hrow[i] = (float)hf[(long)(rbase + r) * kH + k];
    }
    __syncthreads();

    float pv = bp[oc];
    #pragma unroll 8
    for (int k = 0; k < kH; ++k)
      pv += hrow[orow * kH + k] * Wp[(long)k * kO + oc];

    red[tid] = pv;
    __syncthreads();
    float m = -1e30f;
    for (int j = 0; j < 128; ++j) m = fmaxf(m, red[orow * 128 + j]);
    __syncthreads();
    float e = __expf(pv - m);
    red[tid] = e;
    __syncthreads();
    float s = 0.f;
    for (int j = 0; j < 128; ++j) s += red[orow * 128 + j];
    out[(long)(rbase + orow) * kO + oc] = e / s;
  }
}

extern "C" void kernel_launch(void* const* d_in, const int* in_sizes, int n_in,
                              void* d_out, int out_size, void* d_ws, size_t ws_size,
                              hipStream_t stream) {
  const float* x  = (const float*)d_in[0];
  const float* Wx = (const float*)d_in[1];
  const float* Wh = (const float*)d_in[2];
  const float* b  = (const float*)d_in[3];
  const float* Wp = (const float*)d_in[4];
  const float* bp = (const float*)d_in[5];
  float* out = (float*)d_out;
  float* ws  = (float*)d_ws;

  void* args[] = { &x, &Wx, &Wh, &b, &Wp, &bp, &out, &ws };
  hipLaunchCooperativeKernel((void*)lstm_fused, dim3(128), dim3(256), args, 0, stream);
}